// Round 5
// baseline (393.954 us; speedup 1.0000x reference)
//
#include <hip/hip_runtime.h>
#include <hip/hip_bf16.h>
#include <math.h>

#define BB 64
#define SS 500
#define DIN 64
#define DD 128
#define HH 8
#define HDIM 16
#define HALF_ 5
#define WINW 11
#define LL 2
#define FF 512
#define MM (BB*SS)          // 32000 rows
#define LN_EPS 1e-12f

typedef __attribute__((ext_vector_type(8))) short short8;   // 8 bf16 = 4 VGPR
typedef __attribute__((ext_vector_type(4))) float f32x4;

// ---------------------------------------------------------------------------
// Weight prep: fp32 W[K][N] -> bf16 W^T[N][K]. m=0..11: layer weights;
// m=12: W_in (64x128 -> 128x64 at offset 393216).
// ---------------------------------------------------------------------------
__global__ __launch_bounds__(256) void k_prep(
    const float* __restrict__ Wq, const float* __restrict__ Wk,
    const float* __restrict__ Wv, const float* __restrict__ Wo,
    const float* __restrict__ Wi, const float* __restrict__ Wo2,
    const float* __restrict__ Win, __hip_bfloat16* __restrict__ wT)
{
    const int m = blockIdx.y;        // 0..12
    const float* src; int Kd, Nd, kshift, doff;
    if (m == 12) {
        src = Win; Kd = 64; Nd = 128; kshift = 6; doff = 393216;
    } else {
        const int l = m / 6, t = m % 6;
        int toff;
        switch (t) {
          case 0:  src = Wq  + l*16384; Kd=128; Nd=128; kshift=7; toff=0;      break;
          case 1:  src = Wk  + l*16384; Kd=128; Nd=128; kshift=7; toff=16384;  break;
          case 2:  src = Wv  + l*16384; Kd=128; Nd=128; kshift=7; toff=32768;  break;
          case 3:  src = Wo  + l*16384; Kd=128; Nd=128; kshift=7; toff=49152;  break;
          case 4:  src = Wi  + l*65536; Kd=128; Nd=512; kshift=7; toff=65536;  break;
          default: src = Wo2 + l*65536; Kd=512; Nd=128; kshift=9; toff=131072; break;
        }
        doff = l*196608 + toff;
    }
    __hip_bfloat16* dst = wT + doff;
    const int NK = Kd * Nd;
    int e = (blockIdx.x * 256 + threadIdx.x) * 4;
    if (e >= NK) return;
    #pragma unroll
    for (int j = 0; j < 4; ++j, ++e) {
        int n = e >> kshift, kx = e & (Kd - 1);
        dst[(size_t)n * Kd + kx] = __float2bfloat16(src[(size_t)kx * Nd + n]);
    }
}

// x fp32 -> bf16
__global__ __launch_bounds__(256) void k_xcvt(
    const float* __restrict__ x, __hip_bfloat16* __restrict__ xbf)
{
    int i = (blockIdx.x * 256 + threadIdx.x) * 4;
    if (i >= MM * DIN) return;
    float4 v = *(const float4*)(x + i);
    ushort4 o;
    __hip_bfloat16 t0 = __float2bfloat16(v.x); o.x = *(unsigned short*)&t0;
    __hip_bfloat16 t1 = __float2bfloat16(v.y); o.y = *(unsigned short*)&t1;
    __hip_bfloat16 t2 = __float2bfloat16(v.z); o.z = *(unsigned short*)&t2;
    __hip_bfloat16 t3 = __float2bfloat16(v.w); o.w = *(unsigned short*)&t3;
    *(ushort4*)(xbf + i) = o;
}

// ---------------------------------------------------------------------------
// MFMA GEMM mainloop (64 rows x 128 cols, 4 waves, 16x16x32 bf16, BK=64)
// ---------------------------------------------------------------------------
#define GEMM_MAIN(Abf, lda, Kdim, WTbf, ldw, n0w)                             \
    __shared__ __align__(16) __hip_bfloat16 As[64][72];                       \
    __shared__ __align__(16) __hip_bfloat16 Ws[128][72];                      \
    const int tid = threadIdx.x;                                              \
    const int wid = tid >> 6;                                                 \
    const int l15 = tid & 15;                                                 \
    const int l4  = (tid & 63) >> 4;                                          \
    const int m0  = blockIdx.x * 64;                                          \
    f32x4 acc[8];                                                             \
    _Pragma("unroll")                                                         \
    for (int n = 0; n < 8; ++n) acc[n] = (f32x4){0.f, 0.f, 0.f, 0.f};         \
    for (int k0 = 0; k0 < (Kdim); k0 += 64) {                                 \
        _Pragma("unroll")                                                     \
        for (int it = 0; it < 2; ++it) {                                      \
            int lin = it * 2048 + tid * 8;                                    \
            int r = lin >> 6, c = lin & 63;                                   \
            *(uint4*)&As[r][c] =                                              \
                *(const uint4*)((Abf) + (size_t)(m0 + r) * (lda) + k0 + c);   \
        }                                                                     \
        _Pragma("unroll")                                                     \
        for (int it = 0; it < 4; ++it) {                                      \
            int lin = it * 2048 + tid * 8;                                    \
            int r = lin >> 6, c = lin & 63;                                   \
            *(uint4*)&Ws[r][c] =                                              \
                *(const uint4*)((WTbf) + (size_t)((n0w) + r) * (ldw) + k0 + c); \
        }                                                                     \
        __syncthreads();                                                      \
        _Pragma("unroll")                                                     \
        for (int kc = 0; kc < 64; kc += 32) {                                 \
            short8 a0 = *(const short8*)&As[wid * 16 + l15][kc + l4 * 8];     \
            _Pragma("unroll")                                                 \
            for (int n = 0; n < 8; ++n) {                                     \
                short8 bf = *(const short8*)&Ws[n * 16 + l15][kc + l4 * 8];   \
                acc[n] = __builtin_amdgcn_mfma_f32_16x16x32_bf16(a0, bf, acc[n], 0, 0, 0); \
            }                                                                 \
        }                                                                     \
        __syncthreads();                                                      \
    }
// acc[n][q] -> row = m0 + wid*16 + l4*4 + q, col = n*16 + l15

// ---------------------------------------------------------------------------
// Embedding via MFMA: h = LN(xbf @ WinT^T + b_in + pos[2+s] + tt); dual store
// ---------------------------------------------------------------------------
__global__ __launch_bounds__(256, 4) void k_embed(
    const __hip_bfloat16* __restrict__ xbf, const __hip_bfloat16* __restrict__ wInT,
    const float* __restrict__ bin, const float* __restrict__ pos,
    const float* __restrict__ tt, const float* __restrict__ g,
    const float* __restrict__ be, float* __restrict__ h,
    __hip_bfloat16* __restrict__ hbf)
{
    GEMM_MAIN(xbf, DIN, DIN, wInT, DIN, 0)
    #pragma unroll
    for (int qq = 0; qq < 4; ++qq) {
        const int row = m0 + wid * 16 + l4 * 4 + qq;
        const int s = row % SS;
        float vals[8]; float s1 = 0.f, s2 = 0.f;
        #pragma unroll
        for (int n = 0; n < 8; ++n) {
            const int col = n * 16 + l15;
            float val = acc[n][qq] + bin[col] + tt[col] + pos[(size_t)(2 + s) * DD + col];
            vals[n] = val; s1 += val; s2 += val * val;
        }
        #pragma unroll
        for (int o = 1; o < 16; o <<= 1) {
            s1 += __shfl_xor(s1, o, 16);
            s2 += __shfl_xor(s2, o, 16);
        }
        const float mean = s1 * (1.0f / DD);
        const float var  = s2 * (1.0f / DD) - mean * mean;
        const float rstd = rsqrtf(var + LN_EPS);
        #pragma unroll
        for (int n = 0; n < 8; ++n) {
            const int col = n * 16 + l15;
            const float o = (vals[n] - mean) * rstd * g[col] + be[col];
            h[(size_t)row * DD + col]   = o;
            hbf[(size_t)row * DD + col] = __float2bfloat16(o);
        }
    }
}

// ---------------------------------------------------------------------------
// Fused per-layer attention block: QKV (MFMA) -> windowed softmax -> PV ->
// Wo (MFMA) + bias + residual + LN -> dual store. Block = 32 queries of one
// batch; staged h rows [s0-5, s0+43) (48 rows incl halo). 256 thr, 4 waves.
// ---------------------------------------------------------------------------
__global__ __launch_bounds__(256) void k_fused(
    const __hip_bfloat16* __restrict__ hin,
    const __hip_bfloat16* __restrict__ wTq, const __hip_bfloat16* __restrict__ wTk,
    const __hip_bfloat16* __restrict__ wTv, const __hip_bfloat16* __restrict__ wTo,
    const float* __restrict__ bq, const float* __restrict__ bk,
    const float* __restrict__ bv, const float* __restrict__ bo,
    const float* __restrict__ hres,
    const float* __restrict__ g1, const float* __restrict__ bt1,
    float* __restrict__ hout, __hip_bfloat16* __restrict__ hbfout)
{
    __shared__ __align__(16) char smem[49472];
    __hip_bfloat16* kS   = (__hip_bfloat16*)smem;            // [48][136]
    __hip_bfloat16* vS   = (__hip_bfloat16*)(smem + 13056);  // [48][136]
    __hip_bfloat16* hS   = (__hip_bfloat16*)(smem + 26112);  // [48][136]; reused as ctxS[32][136]
    __hip_bfloat16* qS   = (__hip_bfloat16*)(smem + 39168);  // [32][136]
    float*          pS   = (float*)(smem + 47872);           // [16][17]
    float*          rsum = (float*)(smem + 48960);           // [2][2][16][2]
    __hip_bfloat16* ctxS = hS;

    const int tid = threadIdx.x;
    const int wid = tid >> 6, l15 = tid & 15, l4 = (tid & 63) >> 4;
    const int b = blockIdx.y;
    const int s0 = blockIdx.x * 32;

    // stage 48 rows of hin (halo +-5), zero-pad OOB: 768 uint4
    #pragma unroll
    for (int it = 0; it < 3; ++it) {
        int lin = it * 256 + tid;            // 0..767
        int r = lin >> 4, c8 = (lin & 15) * 8;
        int s = s0 - 5 + r;
        uint4 val = {0, 0, 0, 0};
        if (s >= 0 && s < SS)
            val = *(const uint4*)(hin + ((size_t)(b * SS + s)) * DD + c8);
        *(uint4*)&hS[r * 136 + c8] = val;
    }
    __syncthreads();

    // ---- QKV: 9 jobs (out 0..2 x rowtile 0..2), B-frags from global (L2) ----
    for (int j = wid; j < 9; j += 4) {
        const int out = j / 3, rt = j % 3;
        const __hip_bfloat16* WT = (out == 0) ? wTq : ((out == 1) ? wTk : wTv);
        const float* bias = (out == 0) ? bq : ((out == 1) ? bk : bv);
        for (int n = 0; n < 8; ++n) {
            f32x4 a = (f32x4){0.f, 0.f, 0.f, 0.f};
            #pragma unroll
            for (int kc = 0; kc < 4; ++kc) {
                short8 af  = *(const short8*)&hS[(rt * 16 + l15) * 136 + kc * 32 + l4 * 8];
                short8 bfg = *(const short8*)(WT + (size_t)(n * 16 + l15) * DD + kc * 32 + l4 * 8);
                a = __builtin_amdgcn_mfma_f32_16x16x32_bf16(af, bfg, a, 0, 0, 0);
            }
            const int col = n * 16 + l15;
            const float bcol = bias[col];
            #pragma unroll
            for (int qq = 0; qq < 4; ++qq) {
                const int row = rt * 16 + l4 * 4 + qq;
                const float val = a[qq] + bcol;
                if (out == 0) {
                    if (row >= 5 && row < 37)
                        qS[(row - 5) * 136 + col] = __float2bfloat16(val * 0.25f);
                } else if (out == 1) {
                    kS[row * 136 + col] = __float2bfloat16(val);
                } else {
                    vS[row * 136 + col] = __float2bfloat16(val);
                }
            }
        }
    }
    __syncthreads();

    // ---- windowed attention: group g = query, lane wl = window pos / dim ----
    {
        const int g = tid >> 4, wl = tid & 15;
        for (int qh = 0; qh < 2; ++qh) {
            const int qrow = qh * 16 + g;
            const int sq = s0 + qrow;
            const int sk = sq + wl - HALF_;
            const bool valid = (wl < WINW) && (sq < SS) && (sk >= 0) && (sk < SS);
            #pragma unroll
            for (int hh = 0; hh < 8; ++hh) {
                const int off = hh * 16;
                float sc = 0.f;
                const unsigned* qp = (const unsigned*)&qS[qrow * 136 + off];
                const unsigned* kp = (const unsigned*)&kS[(qrow + wl) * 136 + off];
                #pragma unroll
                for (int d2 = 0; d2 < 8; ++d2) {
                    unsigned qu = qp[d2], ku = kp[d2];
                    sc += __uint_as_float(qu << 16) * __uint_as_float(ku << 16)
                        + __uint_as_float(qu & 0xffff0000u) * __uint_as_float(ku & 0xffff0000u);
                }
                sc = valid ? sc : -INFINITY;
                float mx = sc;
                #pragma unroll
                for (int o = 1; o < 16; o <<= 1) mx = fmaxf(mx, __shfl_xor(mx, o, 16));
                float p = valid ? __expf(sc - mx) : 0.f;
                float den = p;
                #pragma unroll
                for (int o = 1; o < 16; o <<= 1) den += __shfl_xor(den, o, 16);
                const float inv = (den > 0.f) ? 1.f / den : 0.f;
                pS[g * 17 + wl] = p;
                // PV: lane = dim
                float cd = 0.f;
                #pragma unroll
                for (int w2 = 0; w2 < WINW; ++w2)
                    cd += pS[g * 17 + w2] * __bfloat162float(vS[(qrow + w2) * 136 + off + wl]);
                ctxS[qrow * 136 + off + wl] = __float2bfloat16(cd * inv);
            }
        }
    }
    __syncthreads();

    // ---- Wo GEMM + bias + residual + LN ----
    const int rt2 = wid & 1, nh = wid >> 1;
    f32x4 ac[4];
    #pragma unroll
    for (int n4 = 0; n4 < 4; ++n4) {
        ac[n4] = (f32x4){0.f, 0.f, 0.f, 0.f};
        const int n = nh * 4 + n4;
        #pragma unroll
        for (int kc = 0; kc < 4; ++kc) {
            short8 af  = *(const short8*)&ctxS[(rt2 * 16 + l15) * 136 + kc * 32 + l4 * 8];
            short8 bfg = *(const short8*)(wTo + (size_t)(n * 16 + l15) * DD + kc * 32 + l4 * 8);
            ac[n4] = __builtin_amdgcn_mfma_f32_16x16x32_bf16(af, bfg, ac[n4], 0, 0, 0);
        }
    }
    float vals[4][4];
    #pragma unroll
    for (int qq = 0; qq < 4; ++qq) {
        const int r16 = l4 * 4 + qq;
        const int qrow = rt2 * 16 + r16;
        const int sq = s0 + qrow;
        const bool vr = (sq < SS);
        float s1 = 0.f, s2 = 0.f;
        #pragma unroll
        for (int n4 = 0; n4 < 4; ++n4) {
            const int col = (nh * 4 + n4) * 16 + l15;
            const float resv = vr ? hres[((size_t)(b * SS + sq)) * DD + col] : 0.f;
            const float val = ac[n4][qq] + bo[col] + resv;
            vals[qq][n4] = val; s1 += val; s2 += val * val;
        }
        #pragma unroll
        for (int o = 1; o < 16; o <<= 1) {
            s1 += __shfl_xor(s1, o, 16);
            s2 += __shfl_xor(s2, o, 16);
        }
        if (l15 == 0) {
            rsum[rt2 * 64 + nh * 32 + r16 * 2]     = s1;
            rsum[rt2 * 64 + nh * 32 + r16 * 2 + 1] = s2;
        }
    }
    __syncthreads();
    #pragma unroll
    for (int qq = 0; qq < 4; ++qq) {
        const int r16 = l4 * 4 + qq;
        const int qrow = rt2 * 16 + r16;
        const int sq = s0 + qrow;
        if (sq >= SS) continue;
        const float S1 = rsum[rt2 * 64 + r16 * 2]     + rsum[rt2 * 64 + 32 + r16 * 2];
        const float S2 = rsum[rt2 * 64 + r16 * 2 + 1] + rsum[rt2 * 64 + 32 + r16 * 2 + 1];
        const float mean = S1 * (1.0f / DD);
        const float var  = S2 * (1.0f / DD) - mean * mean;
        const float rstd = rsqrtf(var + LN_EPS);
        #pragma unroll
        for (int n4 = 0; n4 < 4; ++n4) {
            const int col = (nh * 4 + n4) * 16 + l15;
            const float o = (vals[qq][n4] - mean) * rstd * g1[col] + bt1[col];
            hout[((size_t)(b * SS + sq)) * DD + col]   = o;
            hbfout[((size_t)(b * SS + sq)) * DD + col] = __float2bfloat16(o);
        }
    }
}

// FFN1: N=512 tiled by blockIdx.y, gelu(exact), bf16 out
__global__ __launch_bounds__(256, 4) void k_gemm_gelu(
    const __hip_bfloat16* __restrict__ hbf,
    const __hip_bfloat16* __restrict__ wTi,
    const float* __restrict__ bias, __hip_bfloat16* __restrict__ hid)
{
    const int n0g = blockIdx.y * 128;
    GEMM_MAIN(hbf, DD, DD, wTi, DD, n0g)
    #pragma unroll
    for (int qq = 0; qq < 4; ++qq) {
        const int row = m0 + wid * 16 + l4 * 4 + qq;
        #pragma unroll
        for (int n = 0; n < 8; ++n) {
            const int col = n0g + n * 16 + l15;
            float val = acc[n][qq] + bias[col];
            val = 0.5f * val * (1.f + erff(val * 0.70710678118f));
            hid[(size_t)row * FF + col] = __float2bfloat16(val);
        }
    }
}

// FFN2 + bias + residual + LayerNorm, dual store (in-place safe: row-exclusive)
__global__ __launch_bounds__(256, 4) void k_gemm_lnres(
    const __hip_bfloat16* __restrict__ Abf, int lda, int Kdim,
    const __hip_bfloat16* __restrict__ WT,
    const float* __restrict__ bias, const float* __restrict__ res,
    const float* __restrict__ g, const float* __restrict__ bt,
    float* __restrict__ outF, __hip_bfloat16* __restrict__ outB)
{
    GEMM_MAIN(Abf, lda, Kdim, WT, Kdim, 0)
    #pragma unroll
    for (int qq = 0; qq < 4; ++qq) {
        const int row = m0 + wid * 16 + l4 * 4 + qq;
        float vals[8]; float s1 = 0.f, s2 = 0.f;
        #pragma unroll
        for (int n = 0; n < 8; ++n) {
            const int col = n * 16 + l15;
            float val = acc[n][qq] + bias[col] + res[(size_t)row * DD + col];
            vals[n] = val; s1 += val; s2 += val * val;
        }
        #pragma unroll
        for (int o = 1; o < 16; o <<= 1) {
            s1 += __shfl_xor(s1, o, 16);
            s2 += __shfl_xor(s2, o, 16);
        }
        const float mean = s1 * (1.0f / DD);
        const float var  = s2 * (1.0f / DD) - mean * mean;
        const float rstd = rsqrtf(var + LN_EPS);
        #pragma unroll
        for (int n = 0; n < 8; ++n) {
            const int col = n * 16 + l15;
            const float o = (vals[n] - mean) * rstd * g[col] + bt[col];
            outF[(size_t)row * DD + col] = o;
            outB[(size_t)row * DD + col] = __float2bfloat16(o);
        }
    }
}

// ---------------------------------------------------------------------------
// Final: out[b] = mean_s(h[b,s,:]) @ W_cls + b_cls   (fp32 exact)
// ---------------------------------------------------------------------------
__global__ __launch_bounds__(128) void k_final(
    const float* __restrict__ h, const float* __restrict__ Wc,
    const float* __restrict__ bc, float* __restrict__ out)
{
    const int b = blockIdx.x, d = threadIdx.x;
    float p = 0.f;
    for (int s = 0; s < SS; ++s) p += h[((size_t)(b * SS + s)) * DD + d];
    p *= (1.0f / SS);
    float l0 = p * Wc[d * 2 + 0];
    float l1 = p * Wc[d * 2 + 1];
    #pragma unroll
    for (int off = 1; off < 64; off <<= 1) {
        l0 += __shfl_xor(l0, off);
        l1 += __shfl_xor(l1, off);
    }
    __shared__ float r[2][2];
    const int wid = d >> 6;
    if ((d & 63) == 0) { r[wid][0] = l0; r[wid][1] = l1; }
    __syncthreads();
    if (d == 0) {
        out[b * 2 + 0] = r[0][0] + r[1][0] + bc[0];
        out[b * 2 + 1] = r[0][1] + r[1][1] + bc[1];
    }
}

// ---------------------------------------------------------------------------
extern "C" void kernel_launch(void* const* d_in, const int* in_sizes, int n_in,
                              void* d_out, int out_size, void* d_ws, size_t ws_size,
                              hipStream_t stream)
{
    const float* x      = (const float*)d_in[0];
    const float* W_in   = (const float*)d_in[1];
    const float* b_in   = (const float*)d_in[2];
    const float* pos    = (const float*)d_in[3];
    const float* tt     = (const float*)d_in[4];
    const float* lng    = (const float*)d_in[5];
    const float* lnb    = (const float*)d_in[6];
    const float* Wq     = (const float*)d_in[7];
    const float* bq     = (const float*)d_in[8];
    const float* Wk     = (const float*)d_in[9];
    const float* bk     = (const float*)d_in[10];
    const float* Wv     = (const float*)d_in[11];
    const float* bv     = (const float*)d_in[12];
    const float* Wo     = (const float*)d_in[13];
    const float* bo     = (const float*)d_in[14];
    const float* ln1g   = (const float*)d_in[15];
    const float* ln1b   = (const float*)d_in[16];
    const float* Wi     = (const float*)d_in[17];
    const float* bi     = (const float*)d_in[18];
    const float* Wo2    = (const float*)d_in[19];
    const float* bo2    = (const float*)d_in[20];
    const float* ln2g   = (const float*)d_in[21];
    const float* ln2b   = (const float*)d_in[22];
    const float* Wc     = (const float*)d_in[23];
    const float* bc     = (const float*)d_in[24];

    // workspace (float-index offsets), total ~86.8 MB (ws >= 98.3 MB proven R1)
    float*          ws   = (float*)d_ws;
    float*          hA   = ws;                                  // 16.384 MB
    __hip_bfloat16* hbA  = (__hip_bfloat16*)(ws + 4096000);     //  8.192 MB
    __hip_bfloat16* xbf  = (__hip_bfloat16*)(ws + 6144000);     //  4.096 MB
    __hip_bfloat16* wT   = (__hip_bfloat16*)(ws + 7168000);     //  0.803 MB
    __hip_bfloat16* hid  = (__hip_bfloat16*)(ws + 7368704);     // 32.768 MB
    float*          hB   = ws + 15560704;                       // 16.384 MB
    __hip_bfloat16* hbB  = (__hip_bfloat16*)(ws + 19656704);    //  8.192 MB

    k_prep<<<dim3(64, 13), 256, 0, stream>>>(Wq, Wk, Wv, Wo, Wi, Wo2, W_in, wT);
    k_xcvt<<<2000, 256, 0, stream>>>(x, xbf);
    k_embed<<<MM / 64, 256, 0, stream>>>(xbf, wT + 393216, b_in, pos, tt, lng, lnb,
                                         hA, hbA);

    float* hI = hA; __hip_bfloat16* hbI = hbA;
    float* hO = hB; __hip_bfloat16* hbO = hbB;
    for (int l = 0; l < LL; ++l) {
        const __hip_bfloat16* wTq  = wT + l * 196608;
        const __hip_bfloat16* wTk  = wTq + 16384;
        const __hip_bfloat16* wTv  = wTq + 32768;
        const __hip_bfloat16* wTo  = wTq + 49152;
        const __hip_bfloat16* wTi  = wTq + 65536;
        const __hip_bfloat16* wTo2 = wTq + 131072;

        k_fused<<<dim3(16, BB), 256, 0, stream>>>(
            hbI, wTq, wTk, wTv, wTo,
            bq + l * DD, bk + l * DD, bv + l * DD, bo + l * DD,
            hI, ln1g + l * DD, ln1b + l * DD, hO, hbO);

        k_gemm_gelu<<<dim3(MM / 64, 4), 256, 0, stream>>>(
            hbO, wTi, bi + l * FF, hid);

        k_gemm_lnres<<<dim3(MM / 64, 1), 256, 0, stream>>>(
            hid, FF, FF, wTo2, bo2 + l * DD, hO, ln2g + l * DD, ln2b + l * DD,
            hO, hbO);

        // ping-pong
        float* tf = hI; hI = hO; hO = tf;
        __hip_bfloat16* tb = hbI; hbI = hbO; hbO = tb;
    }

    k_final<<<BB, 128, 0, stream>>>(hI, Wc, bc, (float*)d_out);
}

// Round 6
// 336.820 us; speedup vs baseline: 1.1696x; 1.1696x over previous
//
#include <hip/hip_runtime.h>
#include <hip/hip_bf16.h>
#include <math.h>

#define BB 64
#define SS 500
#define DIN 64
#define DD 128
#define HH 8
#define HDIM 16
#define HALF_ 5
#define WINW 11
#define LL 2
#define FF 512
#define MM (BB*SS)          // 32000 rows
#define LN_EPS 1e-12f

typedef __attribute__((ext_vector_type(8))) short short8;   // 8 bf16 = 4 VGPR
typedef __attribute__((ext_vector_type(4))) float f32x4;

// ---------------------------------------------------------------------------
// Weight prep: fp32 W[K][N] -> bf16 W^T[N][K]. m=0..11: layer weights;
// m=12: W_in (64x128 -> 128x64 at offset 393216).
// ---------------------------------------------------------------------------
__global__ __launch_bounds__(256) void k_prep(
    const float* __restrict__ Wq, const float* __restrict__ Wk,
    const float* __restrict__ Wv, const float* __restrict__ Wo,
    const float* __restrict__ Wi, const float* __restrict__ Wo2,
    const float* __restrict__ Win, __hip_bfloat16* __restrict__ wT)
{
    const int m = blockIdx.y;        // 0..12
    const float* src; int Kd, Nd, kshift, doff;
    if (m == 12) {
        src = Win; Kd = 64; Nd = 128; kshift = 6; doff = 393216;
    } else {
        const int l = m / 6, t = m % 6;
        int toff;
        switch (t) {
          case 0:  src = Wq  + l*16384; Kd=128; Nd=128; kshift=7; toff=0;      break;
          case 1:  src = Wk  + l*16384; Kd=128; Nd=128; kshift=7; toff=16384;  break;
          case 2:  src = Wv  + l*16384; Kd=128; Nd=128; kshift=7; toff=32768;  break;
          case 3:  src = Wo  + l*16384; Kd=128; Nd=128; kshift=7; toff=49152;  break;
          case 4:  src = Wi  + l*65536; Kd=128; Nd=512; kshift=7; toff=65536;  break;
          default: src = Wo2 + l*65536; Kd=512; Nd=128; kshift=9; toff=131072; break;
        }
        doff = l*196608 + toff;
    }
    __hip_bfloat16* dst = wT + doff;
    const int NK = Kd * Nd;
    int e = (blockIdx.x * 256 + threadIdx.x) * 4;
    if (e >= NK) return;
    #pragma unroll
    for (int j = 0; j < 4; ++j, ++e) {
        int n = e >> kshift, kx = e & (Kd - 1);
        dst[(size_t)n * Kd + kx] = __float2bfloat16(src[(size_t)kx * Nd + n]);
    }
}

// x fp32 -> bf16
__global__ __launch_bounds__(256) void k_xcvt(
    const float* __restrict__ x, __hip_bfloat16* __restrict__ xbf)
{
    int i = (blockIdx.x * 256 + threadIdx.x) * 4;
    if (i >= MM * DIN) return;
    float4 v = *(const float4*)(x + i);
    ushort4 o;
    __hip_bfloat16 t0 = __float2bfloat16(v.x); o.x = *(unsigned short*)&t0;
    __hip_bfloat16 t1 = __float2bfloat16(v.y); o.y = *(unsigned short*)&t1;
    __hip_bfloat16 t2 = __float2bfloat16(v.z); o.z = *(unsigned short*)&t2;
    __hip_bfloat16 t3 = __float2bfloat16(v.w); o.w = *(unsigned short*)&t3;
    *(ushort4*)(xbf + i) = o;
}

// ---------------------------------------------------------------------------
// MFMA GEMM mainloop (64 rows x 128 cols, 4 waves, 16x16x32 bf16, BK=64)
// ---------------------------------------------------------------------------
#define GEMM_MAIN(Abf, lda, Kdim, WTbf, ldw, n0w)                             \
    __shared__ __align__(16) __hip_bfloat16 As[64][72];                       \
    __shared__ __align__(16) __hip_bfloat16 Ws[128][72];                      \
    const int tid = threadIdx.x;                                              \
    const int wid = tid >> 6;                                                 \
    const int l15 = tid & 15;                                                 \
    const int l4  = (tid & 63) >> 4;                                          \
    const int m0  = blockIdx.x * 64;                                          \
    f32x4 acc[8];                                                             \
    _Pragma("unroll")                                                         \
    for (int n = 0; n < 8; ++n) acc[n] = (f32x4){0.f, 0.f, 0.f, 0.f};         \
    for (int k0 = 0; k0 < (Kdim); k0 += 64) {                                 \
        _Pragma("unroll")                                                     \
        for (int it = 0; it < 2; ++it) {                                      \
            int lin = it * 2048 + tid * 8;                                    \
            int r = lin >> 6, c = lin & 63;                                   \
            *(uint4*)&As[r][c] =                                              \
                *(const uint4*)((Abf) + (size_t)(m0 + r) * (lda) + k0 + c);   \
        }                                                                     \
        _Pragma("unroll")                                                     \
        for (int it = 0; it < 4; ++it) {                                      \
            int lin = it * 2048 + tid * 8;                                    \
            int r = lin >> 6, c = lin & 63;                                   \
            *(uint4*)&Ws[r][c] =                                              \
                *(const uint4*)((WTbf) + (size_t)((n0w) + r) * (ldw) + k0 + c); \
        }                                                                     \
        __syncthreads();                                                      \
        _Pragma("unroll")                                                     \
        for (int kc = 0; kc < 64; kc += 32) {                                 \
            short8 a0 = *(const short8*)&As[wid * 16 + l15][kc + l4 * 8];     \
            _Pragma("unroll")                                                 \
            for (int n = 0; n < 8; ++n) {                                     \
                short8 bf = *(const short8*)&Ws[n * 16 + l15][kc + l4 * 8];   \
                acc[n] = __builtin_amdgcn_mfma_f32_16x16x32_bf16(a0, bf, acc[n], 0, 0, 0); \
            }                                                                 \
        }                                                                     \
        __syncthreads();                                                      \
    }
// acc[n][q] -> row = m0 + wid*16 + l4*4 + q, col = n*16 + l15

// ---------------------------------------------------------------------------
// Embedding via MFMA: h = LN(xbf @ WinT^T + b_in + pos[2+s] + tt); dual store
// ---------------------------------------------------------------------------
__global__ __launch_bounds__(256, 4) void k_embed(
    const __hip_bfloat16* __restrict__ xbf, const __hip_bfloat16* __restrict__ wInT,
    const float* __restrict__ bin, const float* __restrict__ pos,
    const float* __restrict__ tt, const float* __restrict__ g,
    const float* __restrict__ be, float* __restrict__ h,
    __hip_bfloat16* __restrict__ hbf)
{
    GEMM_MAIN(xbf, DIN, DIN, wInT, DIN, 0)
    #pragma unroll
    for (int qq = 0; qq < 4; ++qq) {
        const int row = m0 + wid * 16 + l4 * 4 + qq;
        const int s = row % SS;
        float vals[8]; float s1 = 0.f, s2 = 0.f;
        #pragma unroll
        for (int n = 0; n < 8; ++n) {
            const int col = n * 16 + l15;
            float val = acc[n][qq] + bin[col] + tt[col] + pos[(size_t)(2 + s) * DD + col];
            vals[n] = val; s1 += val; s2 += val * val;
        }
        #pragma unroll
        for (int o = 1; o < 16; o <<= 1) {
            s1 += __shfl_xor(s1, o, 16);
            s2 += __shfl_xor(s2, o, 16);
        }
        const float mean = s1 * (1.0f / DD);
        const float var  = s2 * (1.0f / DD) - mean * mean;
        const float rstd = rsqrtf(var + LN_EPS);
        #pragma unroll
        for (int n = 0; n < 8; ++n) {
            const int col = n * 16 + l15;
            const float o = (vals[n] - mean) * rstd * g[col] + be[col];
            h[(size_t)row * DD + col]   = o;
            hbf[(size_t)row * DD + col] = __float2bfloat16(o);
        }
    }
}

// ---------------------------------------------------------------------------
// Fused per-layer attention block, 8-wave version:
//   QKV (72 balanced MFMA triples) -> single-pass windowed softmax/PV ->
//   Wo MFMA + bias + residual + LN -> dual store.
// Block = 32 queries of one batch; stages h rows [s0-5, s0+43). 512 thr.
// LDS 51072 B -> 3 blocks/CU -> up to 24 waves/CU.
// ---------------------------------------------------------------------------
__global__ __launch_bounds__(512, 4) void k_fused(
    const __hip_bfloat16* __restrict__ hin,
    const __hip_bfloat16* __restrict__ wTq, const __hip_bfloat16* __restrict__ wTk,
    const __hip_bfloat16* __restrict__ wTv, const __hip_bfloat16* __restrict__ wTo,
    const float* __restrict__ bq, const float* __restrict__ bk,
    const float* __restrict__ bv, const float* __restrict__ bo,
    const float* __restrict__ hres,
    const float* __restrict__ g1, const float* __restrict__ bt1,
    float* __restrict__ hout, __hip_bfloat16* __restrict__ hbfout)
{
    __shared__ __align__(16) char smem[51072];
    __hip_bfloat16* kS   = (__hip_bfloat16*)smem;            // [48][136]
    __hip_bfloat16* vS   = (__hip_bfloat16*)(smem + 13056);  // [48][136]
    __hip_bfloat16* hS   = (__hip_bfloat16*)(smem + 26112);  // [48][136]; reused as ctxS[32][136]
    __hip_bfloat16* qS   = (__hip_bfloat16*)(smem + 39168);  // [32][136]
    float*          pS   = (float*)(smem + 47872);           // [32][17]
    float*          rsum = (float*)(smem + 50048);           // [2][4][16][2]
    __hip_bfloat16* ctxS = hS;

    const int tid = threadIdx.x;
    const int wid = tid >> 6;                // 0..7
    const int l15 = tid & 15, l4 = (tid & 63) >> 4;
    const int b = blockIdx.y;
    const int s0 = blockIdx.x * 32;

    // stage 48 rows of hin (halo +-5), zero-pad OOB: 768 uint4 over 512 thr
    #pragma unroll
    for (int it = 0; it < 2; ++it) {
        int lin = it * 512 + tid;
        if (lin < 768) {
            int r = lin >> 4, c8 = (lin & 15) * 8;
            int s = s0 - 5 + r;
            uint4 val = {0, 0, 0, 0};
            if (s >= 0 && s < SS)
                val = *(const uint4*)(hin + ((size_t)(b * SS + s)) * DD + c8);
            *(uint4*)&hS[r * 136 + c8] = val;
        }
    }
    __syncthreads();

    // ---- QKV: 72 triples (out,rowtile,n), 9 per wave, interleaved ----
    #pragma unroll
    for (int i = 0; i < 9; ++i) {
        const int t = wid + i * 8;           // 0..71
        const int out = t / 24;
        const int rem = t - out * 24;
        const int rt = rem >> 3, n = rem & 7;
        const __hip_bfloat16* WT = (out == 0) ? wTq : ((out == 1) ? wTk : wTv);
        const float* bias = (out == 0) ? bq : ((out == 1) ? bk : bv);
        f32x4 a = (f32x4){0.f, 0.f, 0.f, 0.f};
        #pragma unroll
        for (int kc = 0; kc < 4; ++kc) {
            short8 af  = *(const short8*)&hS[(rt * 16 + l15) * 136 + kc * 32 + l4 * 8];
            short8 bfg = *(const short8*)(WT + (size_t)(n * 16 + l15) * DD + kc * 32 + l4 * 8);
            a = __builtin_amdgcn_mfma_f32_16x16x32_bf16(af, bfg, a, 0, 0, 0);
        }
        const int col = n * 16 + l15;
        const float bcol = bias[col];
        #pragma unroll
        for (int qq = 0; qq < 4; ++qq) {
            const int row = rt * 16 + l4 * 4 + qq;
            const float val = a[qq] + bcol;
            if (out == 0) {
                if (row >= 5 && row < 37)
                    qS[(row - 5) * 136 + col] = __float2bfloat16(val * 0.25f);
            } else if (out == 1) {
                kS[row * 136 + col] = __float2bfloat16(val);
            } else {
                vS[row * 136 + col] = __float2bfloat16(val);
            }
        }
    }
    __syncthreads();

    // ---- windowed attention, single pass: group g = query (0..31) ----
    {
        const int g = tid >> 4, wl = tid & 15;
        const int sq = s0 + g;
        const int sk = sq + wl - HALF_;
        const bool valid = (wl < WINW) && (sq < SS) && (sk >= 0) && (sk < SS);
        #pragma unroll
        for (int hh = 0; hh < 8; ++hh) {
            const int off = hh * 16;
            float sc = 0.f;
            const unsigned* qp = (const unsigned*)&qS[g * 136 + off];
            const unsigned* kp = (const unsigned*)&kS[(g + wl) * 136 + off];
            #pragma unroll
            for (int d2 = 0; d2 < 8; ++d2) {
                unsigned qu = qp[d2], ku = kp[d2];
                sc += __uint_as_float(qu << 16) * __uint_as_float(ku << 16)
                    + __uint_as_float(qu & 0xffff0000u) * __uint_as_float(ku & 0xffff0000u);
            }
            sc = valid ? sc : -INFINITY;
            float mx = sc;
            #pragma unroll
            for (int o = 1; o < 16; o <<= 1) mx = fmaxf(mx, __shfl_xor(mx, o, 16));
            float p = valid ? __expf(sc - mx) : 0.f;
            float den = p;
            #pragma unroll
            for (int o = 1; o < 16; o <<= 1) den += __shfl_xor(den, o, 16);
            const float inv = (den > 0.f) ? 1.f / den : 0.f;
            pS[g * 17 + wl] = p;
            float cd = 0.f;
            #pragma unroll
            for (int w2 = 0; w2 < WINW; ++w2)
                cd += pS[g * 17 + w2] * __bfloat162float(vS[(g + w2) * 136 + off + wl]);
            ctxS[g * 136 + off + wl] = __float2bfloat16(cd * inv);
        }
    }
    __syncthreads();

    // ---- Wo GEMM + bias + residual + LN: 8 waves = 2 rowtiles x 4 col-qtrs ----
    const int rt2 = wid & 1, nh = wid >> 1;      // nh 0..3 -> cols nh*32..+31
    f32x4 ac[2];
    #pragma unroll
    for (int n4 = 0; n4 < 2; ++n4) {
        ac[n4] = (f32x4){0.f, 0.f, 0.f, 0.f};
        const int n = nh * 2 + n4;
        #pragma unroll
        for (int kc = 0; kc < 4; ++kc) {
            short8 af  = *(const short8*)&ctxS[(rt2 * 16 + l15) * 136 + kc * 32 + l4 * 8];
            short8 bfg = *(const short8*)(wTo + (size_t)(n * 16 + l15) * DD + kc * 32 + l4 * 8);
            ac[n4] = __builtin_amdgcn_mfma_f32_16x16x32_bf16(af, bfg, ac[n4], 0, 0, 0);
        }
    }
    float vals[4][2];
    #pragma unroll
    for (int qq = 0; qq < 4; ++qq) {
        const int r16 = l4 * 4 + qq;
        const int qrow = rt2 * 16 + r16;
        const int sq = s0 + qrow;
        const bool vr = (sq < SS);
        float s1 = 0.f, s2 = 0.f;
        #pragma unroll
        for (int n4 = 0; n4 < 2; ++n4) {
            const int col = (nh * 2 + n4) * 16 + l15;
            const float resv = vr ? hres[((size_t)(b * SS + sq)) * DD + col] : 0.f;
            const float val = ac[n4][qq] + bo[col] + resv;
            vals[qq][n4] = val; s1 += val; s2 += val * val;
        }
        #pragma unroll
        for (int o = 1; o < 16; o <<= 1) {
            s1 += __shfl_xor(s1, o, 16);
            s2 += __shfl_xor(s2, o, 16);
        }
        if (l15 == 0) {
            rsum[((rt2 * 4 + nh) * 16 + r16) * 2]     = s1;
            rsum[((rt2 * 4 + nh) * 16 + r16) * 2 + 1] = s2;
        }
    }
    __syncthreads();
    #pragma unroll
    for (int qq = 0; qq < 4; ++qq) {
        const int r16 = l4 * 4 + qq;
        const int qrow = rt2 * 16 + r16;
        const int sq = s0 + qrow;
        if (sq >= SS) continue;
        float S1 = 0.f, S2 = 0.f;
        #pragma unroll
        for (int j = 0; j < 4; ++j) {
            S1 += rsum[((rt2 * 4 + j) * 16 + r16) * 2];
            S2 += rsum[((rt2 * 4 + j) * 16 + r16) * 2 + 1];
        }
        const float mean = S1 * (1.0f / DD);
        const float var  = S2 * (1.0f / DD) - mean * mean;
        const float rstd = rsqrtf(var + LN_EPS);
        #pragma unroll
        for (int n4 = 0; n4 < 2; ++n4) {
            const int col = (nh * 2 + n4) * 16 + l15;
            const float o = (vals[qq][n4] - mean) * rstd * g1[col] + bt1[col];
            hout[((size_t)(b * SS + sq)) * DD + col]   = o;
            hbfout[((size_t)(b * SS + sq)) * DD + col] = __float2bfloat16(o);
        }
    }
}

// FFN1: N=512 tiled by blockIdx.y, gelu(exact), bf16 out
__global__ __launch_bounds__(256, 4) void k_gemm_gelu(
    const __hip_bfloat16* __restrict__ hbf,
    const __hip_bfloat16* __restrict__ wTi,
    const float* __restrict__ bias, __hip_bfloat16* __restrict__ hid)
{
    const int n0g = blockIdx.y * 128;
    GEMM_MAIN(hbf, DD, DD, wTi, DD, n0g)
    #pragma unroll
    for (int qq = 0; qq < 4; ++qq) {
        const int row = m0 + wid * 16 + l4 * 4 + qq;
        #pragma unroll
        for (int n = 0; n < 8; ++n) {
            const int col = n0g + n * 16 + l15;
            float val = acc[n][qq] + bias[col];
            val = 0.5f * val * (1.f + erff(val * 0.70710678118f));
            hid[(size_t)row * FF + col] = __float2bfloat16(val);
        }
    }
}

// FFN2 + bias + residual + LayerNorm, dual store (in-place safe: row-exclusive)
__global__ __launch_bounds__(256, 4) void k_gemm_lnres(
    const __hip_bfloat16* __restrict__ Abf, int lda, int Kdim,
    const __hip_bfloat16* __restrict__ WT,
    const float* __restrict__ bias, const float* __restrict__ res,
    const float* __restrict__ g, const float* __restrict__ bt,
    float* __restrict__ outF, __hip_bfloat16* __restrict__ outB)
{
    GEMM_MAIN(Abf, lda, Kdim, WT, Kdim, 0)
    #pragma unroll
    for (int qq = 0; qq < 4; ++qq) {
        const int row = m0 + wid * 16 + l4 * 4 + qq;
        float vals[8]; float s1 = 0.f, s2 = 0.f;
        #pragma unroll
        for (int n = 0; n < 8; ++n) {
            const int col = n * 16 + l15;
            float val = acc[n][qq] + bias[col] + res[(size_t)row * DD + col];
            vals[n] = val; s1 += val; s2 += val * val;
        }
        #pragma unroll
        for (int o = 1; o < 16; o <<= 1) {
            s1 += __shfl_xor(s1, o, 16);
            s2 += __shfl_xor(s2, o, 16);
        }
        const float mean = s1 * (1.0f / DD);
        const float var  = s2 * (1.0f / DD) - mean * mean;
        const float rstd = rsqrtf(var + LN_EPS);
        #pragma unroll
        for (int n = 0; n < 8; ++n) {
            const int col = n * 16 + l15;
            const float o = (vals[n] - mean) * rstd * g[col] + bt[col];
            outF[(size_t)row * DD + col] = o;
            outB[(size_t)row * DD + col] = __float2bfloat16(o);
        }
    }
}

// ---------------------------------------------------------------------------
// Final: out[b] = mean_s(h[b,s,:]) @ W_cls + b_cls   (fp32 exact)
// ---------------------------------------------------------------------------
__global__ __launch_bounds__(128) void k_final(
    const float* __restrict__ h, const float* __restrict__ Wc,
    const float* __restrict__ bc, float* __restrict__ out)
{
    const int b = blockIdx.x, d = threadIdx.x;
    float p = 0.f;
    for (int s = 0; s < SS; ++s) p += h[((size_t)(b * SS + s)) * DD + d];
    p *= (1.0f / SS);
    float l0 = p * Wc[d * 2 + 0];
    float l1 = p * Wc[d * 2 + 1];
    #pragma unroll
    for (int off = 1; off < 64; off <<= 1) {
        l0 += __shfl_xor(l0, off);
        l1 += __shfl_xor(l1, off);
    }
    __shared__ float r[2][2];
    const int wid = d >> 6;
    if ((d & 63) == 0) { r[wid][0] = l0; r[wid][1] = l1; }
    __syncthreads();
    if (d == 0) {
        out[b * 2 + 0] = r[0][0] + r[1][0] + bc[0];
        out[b * 2 + 1] = r[0][1] + r[1][1] + bc[1];
    }
}

// ---------------------------------------------------------------------------
extern "C" void kernel_launch(void* const* d_in, const int* in_sizes, int n_in,
                              void* d_out, int out_size, void* d_ws, size_t ws_size,
                              hipStream_t stream)
{
    const float* x      = (const float*)d_in[0];
    const float* W_in   = (const float*)d_in[1];
    const float* b_in   = (const float*)d_in[2];
    const float* pos    = (const float*)d_in[3];
    const float* tt     = (const float*)d_in[4];
    const float* lng    = (const float*)d_in[5];
    const float* lnb    = (const float*)d_in[6];
    const float* Wq     = (const float*)d_in[7];
    const float* bq     = (const float*)d_in[8];
    const float* Wk     = (const float*)d_in[9];
    const float* bk     = (const float*)d_in[10];
    const float* Wv     = (const float*)d_in[11];
    const float* bv     = (const float*)d_in[12];
    const float* Wo     = (const float*)d_in[13];
    const float* bo     = (const float*)d_in[14];
    const float* ln1g   = (const float*)d_in[15];
    const float* ln1b   = (const float*)d_in[16];
    const float* Wi     = (const float*)d_in[17];
    const float* bi     = (const float*)d_in[18];
    const float* Wo2    = (const float*)d_in[19];
    const float* bo2    = (const float*)d_in[20];
    const float* ln2g   = (const float*)d_in[21];
    const float* ln2b   = (const float*)d_in[22];
    const float* Wc     = (const float*)d_in[23];
    const float* bc     = (const float*)d_in[24];

    // workspace (float-index offsets), total ~86.8 MB (ws >= 98.3 MB proven R1)
    float*          ws   = (float*)d_ws;
    float*          hA   = ws;                                  // 16.384 MB
    __hip_bfloat16* hbA  = (__hip_bfloat16*)(ws + 4096000);     //  8.192 MB
    __hip_bfloat16* xbf  = (__hip_bfloat16*)(ws + 6144000);     //  4.096 MB
    __hip_bfloat16* wT   = (__hip_bfloat16*)(ws + 7168000);     //  0.803 MB
    __hip_bfloat16* hid  = (__hip_bfloat16*)(ws + 7368704);     // 32.768 MB
    float*          hB   = ws + 15560704;                       // 16.384 MB
    __hip_bfloat16* hbB  = (__hip_bfloat16*)(ws + 19656704);    //  8.192 MB

    k_prep<<<dim3(64, 13), 256, 0, stream>>>(Wq, Wk, Wv, Wo, Wi, Wo2, W_in, wT);
    k_xcvt<<<2000, 256, 0, stream>>>(x, xbf);
    k_embed<<<MM / 64, 256, 0, stream>>>(xbf, wT + 393216, b_in, pos, tt, lng, lnb,
                                         hA, hbA);

    float* hI = hA; __hip_bfloat16* hbI = hbA;
    float* hO = hB; __hip_bfloat16* hbO = hbB;
    for (int l = 0; l < LL; ++l) {
        const __hip_bfloat16* wTq  = wT + l * 196608;
        const __hip_bfloat16* wTk  = wTq + 16384;
        const __hip_bfloat16* wTv  = wTq + 32768;
        const __hip_bfloat16* wTo  = wTq + 49152;
        const __hip_bfloat16* wTi  = wTq + 65536;
        const __hip_bfloat16* wTo2 = wTq + 131072;

        k_fused<<<dim3(16, BB), 512, 0, stream>>>(
            hbI, wTq, wTk, wTv, wTo,
            bq + l * DD, bk + l * DD, bv + l * DD, bo + l * DD,
            hI, ln1g + l * DD, ln1b + l * DD, hO, hbO);

        k_gemm_gelu<<<dim3(MM / 64, 4), 256, 0, stream>>>(
            hbO, wTi, bi + l * FF, hid);

        k_gemm_lnres<<<dim3(MM / 64, 1), 256, 0, stream>>>(
            hid, FF, FF, wTo2, bo2 + l * DD, hO, ln2g + l * DD, ln2b + l * DD,
            hO, hbO);

        // ping-pong
        float* tf = hI; hI = hO; hO = tf;
        __hip_bfloat16* tb = hbI; hbI = hbO; hbO = tb;
    }

    k_final<<<BB, 128, 0, stream>>>(hI, Wc, bc, (float*)d_out);
}